// Round 6
// baseline (173.592 us; speedup 1.0000x reference)
//
#include <hip/hip_runtime.h>
#include <hip/hip_bf16.h>

#define B_ROWS  2048
#define T_DIM   8
#define IN_DIM  1024
#define OUT_DIM 4096
#define NE      12

#define M_TILE 128
#define N_TILE 128
#define K_STEP 32
#define NSTEP  (IN_DIM / K_STEP)

typedef __attribute__((ext_vector_type(8))) short short8;
typedef __attribute__((ext_vector_type(4))) float f32x4;

union S8U { short8 s; unsigned u[4]; };

// two floats -> packed bf16x2 (v_cvt_pk_bf16_f32, RNE)
__device__ __forceinline__ unsigned cvt2(float a, float b) {
  __hip_bfloat162 h = __float22bfloat162_rn(make_float2(a, b));
  union { __hip_bfloat162 h; unsigned u; } c; c.h = h;
  return c.u;
}

// barrier WITHOUT vmcnt drain: ds-write visibility only, so in-flight
// global loads survive the barrier (T4 pattern).
__device__ __forceinline__ void barrier_lgkm() {
  asm volatile("s_waitcnt lgkmcnt(0)" ::: "memory");
  __builtin_amdgcn_s_barrier();
}

// ---------------- kernel P: transpose Wg[4096][12] -> WgT[12][4096] --------
__global__ __launch_bounds__(256) void wg_transpose(
    const float* __restrict__ Wg, float* __restrict__ wgt)
{
  const int c = blockIdx.x * 256 + threadIdx.x;   // 0..4095
  #pragma unroll
  for (int e = 0; e < NE; ++e)
    wgt[(size_t)e * OUT_DIM + c] = Wg[(size_t)c * NE + e];
}

// ---------------- kernel A: gate (passing version, unchanged) --------------
__global__ __launch_bounds__(256) void gate_kernel(
    const float* __restrict__ t, const float* __restrict__ wgt,
    const float* __restrict__ bg, int* __restrict__ counts,
    int* __restrict__ rowlist)
{
  const int b   = blockIdx.x;
  const int tid = threadIdx.x;
  const float* tb = t + (size_t)b * T_DIM * OUT_DIM;

  float4 m[4];
  #pragma unroll
  for (int it = 0; it < 4; ++it) {
    const int c = (tid + it * 256) * 4;
    float4 s = make_float4(0.f, 0.f, 0.f, 0.f);
    #pragma unroll
    for (int tt = 0; tt < T_DIM; ++tt) {
      const float4 v = *(const float4*)(tb + (size_t)tt * OUT_DIM + c);
      s.x += v.x; s.y += v.y; s.z += v.z; s.w += v.w;
    }
    m[it] = make_float4(s.x * 0.125f, s.y * 0.125f, s.z * 0.125f, s.w * 0.125f);
  }

  float part[NE];
  #pragma unroll
  for (int e = 0; e < NE; ++e) {
    float acc = 0.f;
    #pragma unroll
    for (int it = 0; it < 4; ++it) {
      const int c = (tid + it * 256) * 4;
      const float4 w = *(const float4*)(wgt + (size_t)e * OUT_DIM + c);
      acc += m[it].x * w.x; acc += m[it].y * w.y;
      acc += m[it].z * w.z; acc += m[it].w * w.w;
    }
    part[e] = acc;
  }

  double d[NE];
  #pragma unroll
  for (int e = 0; e < NE; ++e) d[e] = (double)part[e];
  #pragma unroll
  for (int off = 32; off > 0; off >>= 1) {
    #pragma unroll
    for (int e = 0; e < NE; ++e) d[e] += __shfl_down(d[e], off, 64);
  }

  __shared__ double wsred[4][NE];
  const int lane = tid & 63, wave = tid >> 6;
  if (lane == 0) {
    #pragma unroll
    for (int e = 0; e < NE; ++e) wsred[wave][e] = d[e];
  }
  __syncthreads();

  if (tid == 0) {
    double best = -1e300; int bi = 0;
    #pragma unroll
    for (int e = 0; e < NE; ++e) {
      const double v = wsred[0][e] + wsred[1][e] + wsred[2][e] + wsred[3][e] + (double)bg[e];
      if (v > best) { best = v; bi = e; }
    }
    const int pos = atomicAdd(&counts[bi], 1);
    rowlist[bi * B_ROWS + pos] = b;
  }
}

// fallback gate if workspace can't hold WgT
__global__ __launch_bounds__(256) void gate_fallback(
    const float* __restrict__ t, const float* __restrict__ Wg,
    const float* __restrict__ bg, int* __restrict__ counts,
    int* __restrict__ rowlist)
{
  const int b   = blockIdx.x;
  const int tid = threadIdx.x;
  const float* tb = t + (size_t)b * T_DIM * OUT_DIM;

  float part[NE];
  #pragma unroll
  for (int e = 0; e < NE; ++e) part[e] = 0.f;
  #pragma unroll
  for (int it = 0; it < 4; ++it) {
    const int c = (tid + it * 256) * 4;
    float4 s = make_float4(0.f, 0.f, 0.f, 0.f);
    #pragma unroll
    for (int tt = 0; tt < T_DIM; ++tt) {
      const float4 v = *(const float4*)(tb + (size_t)tt * OUT_DIM + c);
      s.x += v.x; s.y += v.y; s.z += v.z; s.w += v.w;
    }
    const float mm[4] = { s.x * 0.125f, s.y * 0.125f, s.z * 0.125f, s.w * 0.125f };
    #pragma unroll
    for (int j = 0; j < 4; ++j) {
      const float* wg = Wg + (size_t)(c + j) * NE;
      #pragma unroll
      for (int e = 0; e < NE; ++e) part[e] += mm[j] * wg[e];
    }
  }
  double d[NE];
  #pragma unroll
  for (int e = 0; e < NE; ++e) d[e] = (double)part[e];
  #pragma unroll
  for (int off = 32; off > 0; off >>= 1) {
    #pragma unroll
    for (int e = 0; e < NE; ++e) d[e] += __shfl_down(d[e], off, 64);
  }
  __shared__ double wsred[4][NE];
  const int lane = tid & 63, wave = tid >> 6;
  if (lane == 0) {
    #pragma unroll
    for (int e = 0; e < NE; ++e) wsred[wave][e] = d[e];
  }
  __syncthreads();
  if (tid == 0) {
    double best = -1e300; int bi = 0;
    #pragma unroll
    for (int e = 0; e < NE; ++e) {
      const double v = wsred[0][e] + wsred[1][e] + wsred[2][e] + wsred[3][e] + (double)bg[e];
      if (v > best) { best = v; bi = e; }
    }
    const int pos = atomicAdd(&counts[bi], 1);
    rowlist[bi * B_ROWS + pos] = b;
  }
}

// ---------------- kernel B: grouped bf16-MFMA GEMM --------------------------
// Round-5 structure with TWO-DEEP prefetch: two static register staging sets
// (A/B), loop unrolled x2. Converting set S waits only on S's loads (counted
// vmcnt); the other set's 20 loads stay in flight across the lgkm-only
// barrier. Per-wave outstanding bytes stay ~8KB continuously instead of
// sawtoothing to zero each step.
__global__ __launch_bounds__(256) void expert_gemm(
    const float* __restrict__ x, const float* __restrict__ W,
    const float* __restrict__ bias, const int* __restrict__ counts,
    const int* __restrict__ rowlist, float* __restrict__ out)
{
  const int e    = blockIdx.z;
  const int cnt  = counts[e];
  const int row0 = blockIdx.y * M_TILE;
  if (row0 >= cnt) return;
  const int c0   = blockIdx.x * N_TILE;
  const int* rl  = rowlist + e * B_ROWS;

  __shared__ short8 xa[2][512];   // 2 x 8 KiB
  __shared__ short8 wb[2][512];   // 2 x 8 KiB

  const int tid  = threadIdx.x;
  const int lane = tid & 63;
  const int wave = tid >> 6;

  // staging geometry: thread owns slots {tid, tid+256} on both sides
  const int sg  = (tid >> 4) & 3;   // k-subgroup
  const int slr = tid & 15;         // lr / lc
  const int smb = tid >> 6;         // frag-block for slot tid (slot tid+256: +4)

  int arow0, arow1;
  {
    const int g0 = row0 + smb * 16 + slr;
    const int g1 = row0 + (smb + 4) * 16 + slr;
    arow0 = rl[g0 < cnt ? g0 : cnt - 1];
    arow1 = rl[g1 < cnt ? g1 : cnt - 1];
  }
  const float* xp0 = x + (size_t)arow0 * IN_DIM + sg * 8;
  const float* xp1 = x + (size_t)arow1 * IN_DIM + sg * 8;
  const float* wp  = W + (size_t)e * IN_DIM * OUT_DIM
                       + (size_t)(sg * 8) * OUT_DIM + c0 + smb * 16 + slr;

  // MFMA geometry
  const int wm = (wave >> 1) * 64;
  const int wn = (wave & 1) * 64;
  const int abase = (wave >> 1) * 256;
  const int bbase = (wave & 1) * 256;

  f32x4 acc[4][4];
  #pragma unroll
  for (int m = 0; m < 4; ++m)
    #pragma unroll
    for (int n = 0; n < 4; ++n)
      #pragma unroll
      for (int q = 0; q < 4; ++q) acc[m][n][q] = 0.f;

  // two static staging register sets (no runtime indexing -> no scratch)
  float4 a0loA, a0hiA, a1loA, a1hiA; float w0A[8], w1A[8];
  float4 a0loB, a0hiB, a1loB, a1hiB; float w0B[8], w1B[8];

#define ISSUE(S, K)                                                     \
  {                                                                     \
    a0lo##S = *(const float4*)(xp0 + (K));                              \
    a0hi##S = *(const float4*)(xp0 + (K) + 4);                          \
    a1lo##S = *(const float4*)(xp1 + (K));                              \
    a1hi##S = *(const float4*)(xp1 + (K) + 4);                          \
    const float* p = wp + (size_t)(K) * OUT_DIM;                        \
    _Pragma("unroll")                                                   \
    for (int j = 0; j < 8; ++j) {                                       \
      w0##S[j] = p[(size_t)j * OUT_DIM];                                \
      w1##S[j] = p[(size_t)j * OUT_DIM + 64];                           \
    }                                                                   \
  }

#define GEMM_STEP(S, BUF, IT)                                           \
  {                                                                     \
    S8U av0, av1, bv0, bv1;                                             \
    av0.u[0] = cvt2(a0lo##S.x, a0lo##S.y);                              \
    av0.u[1] = cvt2(a0lo##S.z, a0lo##S.w);                              \
    av0.u[2] = cvt2(a0hi##S.x, a0hi##S.y);                              \
    av0.u[3] = cvt2(a0hi##S.z, a0hi##S.w);                              \
    av1.u[0] = cvt2(a1lo##S.x, a1lo##S.y);                              \
    av1.u[1] = cvt2(a1lo##S.z, a1lo##S.w);                              \
    av1.u[2] = cvt2(a1hi##S.x, a1hi##S.y);                              \
    av1.u[3] = cvt2(a1hi##S.z, a1hi##S.w);                              \
    _Pragma("unroll")                                                   \
    for (int q = 0; q < 4; ++q) {                                       \
      bv0.u[q] = cvt2(w0##S[2 * q], w0##S[2 * q + 1]);                  \
      bv1.u[q] = cvt2(w1##S[2 * q], w1##S[2 * q + 1]);                  \
    }                                                                   \
    if ((IT) + 2 < NSTEP) ISSUE(S, ((IT) + 2) * K_STEP);                \
    xa[BUF][tid]       = av0.s;                                         \
    xa[BUF][tid + 256] = av1.s;                                         \
    wb[BUF][tid]       = bv0.s;                                         \
    wb[BUF][tid + 256] = bv1.s;                                         \
    barrier_lgkm();                                                     \
    short8 af[4], bf[4];                                                \
    _Pragma("unroll")                                                   \
    for (int m = 0; m < 4; ++m) af[m] = xa[BUF][abase + m * 64 + lane]; \
    _Pragma("unroll")                                                   \
    for (int n = 0; n < 4; ++n) bf[n] = wb[BUF][bbase + n * 64 + lane]; \
    _Pragma("unroll")                                                   \
    for (int m = 0; m < 4; ++m)                                         \
      _Pragma("unroll")                                                 \
      for (int n = 0; n < 4; ++n)                                       \
        acc[m][n] = __builtin_amdgcn_mfma_f32_16x16x32_bf16(            \
            af[m], bf[n], acc[m][n], 0, 0, 0);                          \
  }

  ISSUE(A, 0);
  ISSUE(B, K_STEP);

  for (int it = 0; it < NSTEP; it += 2) {
    GEMM_STEP(A, 0, it);
    GEMM_STEP(B, 1, it + 1);
  }
#undef GEMM_STEP
#undef ISSUE

  // epilogue: C/D layout col = lane&15, row = (lane>>4)*4 + r
  const int lr = lane & 15;
  const int lq = (lane >> 4) * 4;
  float bcol[4];
  #pragma unroll
  for (int n = 0; n < 4; ++n)
    bcol[n] = bias[e * OUT_DIM + c0 + wn + n * 16 + lr];

  #pragma unroll
  for (int m = 0; m < 4; ++m) {
    #pragma unroll
    for (int r = 0; r < 4; ++r) {
      const int gidx = row0 + wm + m * 16 + lq + r;
      if (gidx >= cnt) continue;
      const int grow = rl[gidx];
      float* orow = out + (size_t)grow * OUT_DIM;
      #pragma unroll
      for (int n = 0; n < 4; ++n) {
        const int col = c0 + wn + n * 16 + lr;
        orow[col] = acc[m][n][r] + bcol[n];
      }
    }
  }
}

extern "C" void kernel_launch(void* const* d_in, const int* in_sizes, int n_in,
                              void* d_out, int out_size, void* d_ws, size_t ws_size,
                              hipStream_t stream) {
  (void)in_sizes; (void)n_in; (void)out_size;
  const float* x  = (const float*)d_in[0];
  const float* t  = (const float*)d_in[1];
  const float* W  = (const float*)d_in[2];
  const float* bb = (const float*)d_in[3];
  const float* Wg = (const float*)d_in[4];
  const float* bg = (const float*)d_in[5];
  float* out = (float*)d_out;

  int*   counts  = (int*)d_ws;                                  // 16 ints
  int*   rowlist = (int*)d_ws + 16;                             // 12*2048 ints
  float* wgt     = (float*)((char*)d_ws + 64 + NE * B_ROWS * 4);// 12*4096 f32
  const size_t need = 64 + (size_t)NE * B_ROWS * 4 + (size_t)NE * OUT_DIM * 4;

  hipMemsetAsync(counts, 0, 16 * sizeof(int), stream);
  if (ws_size >= need) {
    wg_transpose<<<OUT_DIM / 256, 256, 0, stream>>>(Wg, wgt);
    gate_kernel<<<B_ROWS, 256, 0, stream>>>(t, wgt, bg, counts, rowlist);
  } else {
    gate_fallback<<<B_ROWS, 256, 0, stream>>>(t, Wg, bg, counts, rowlist);
  }

  dim3 grid(OUT_DIM / N_TILE, (B_ROWS + M_TILE - 1) / M_TILE, NE);
  expert_gemm<<<grid, 256, 0, stream>>>(x, W, bb, counts, rowlist, out);
}